// Round 7
// baseline (150.048 us; speedup 1.0000x reference)
//
#include <hip/hip_runtime.h>

#define NRAYS 8192
typedef const float* fpp;
typedef unsigned int uint;

typedef short bf16x8 __attribute__((ext_vector_type(8)));
typedef int   i32x4  __attribute__((ext_vector_type(4)));
typedef int   i32x2  __attribute__((ext_vector_type(2)));
typedef float f32x4  __attribute__((ext_vector_type(4)));

__device__ __forceinline__ uint bfbits(float f) {          // RNE fp32->bf16 bits
  uint u = __float_as_uint(f);
  return (u + 0x7FFFu + ((u >> 16) & 1u)) >> 16;
}
__device__ __forceinline__ short f2bf(float f) { return (short)bfbits(f); }
// RNE pack (prep/setup only)
__device__ __forceinline__ int pk2(float a, float b) {
  return (int)(bfbits(a) | (bfbits(b) << 16));
}
// 3-op perm pack (round-half-up, R0-baseline-proven for the geo store):
// low short = bf16(a), high short = bf16(b). Pure C++ ops -> hazard-safe on accs.
__device__ __forceinline__ int pkperm(float a, float b) {
  return (int)__builtin_amdgcn_perm(__float_as_uint(b) + 0x8000u,
                                    __float_as_uint(a) + 0x8000u, 0x07060302u);
}
// single-instruction packed convert — ONLY for inputs already filtered through
// a compiler-visible VALU op (e.g. fmaxf); raw MFMA accs must NOT feed this (R3).
__device__ __forceinline__ int cvtpk(float a, float b) {
  int r;
  asm("v_cvt_pk_bf16_f32 %0, %1, %2" : "=v"(r) : "v"(a), "v"(b));
  return r;
}
__device__ __forceinline__ f32x4 MFMA(bf16x8 a, bf16x8 b, f32x4 c) {
  return __builtin_amdgcn_mfma_f32_16x16x32_bf16(a, b, c, 0, 0, 0);
}
__device__ __forceinline__ float waveAllSum(float v) {
#pragma unroll
  for (int off = 32; off > 0; off >>= 1) v += __shfl_xor(v, off, 64);
  return v;
}

// output layout (flat fp32): image[8192,3]@0 depth@24576 dvar@32768 coord@40960
// rgbs[8192,256,3]@65536 clip[8192,32]@6356992
#define OFF_IMG   0
#define OFF_DEPTH 24576
#define OFF_VAR   32768
#define OFF_COORD 40960
#define OFF_RGBS  65536
#define OFF_CLIP  6356992

// c1a M-row permutation: tile t, in-tile row m (=4a+r) sources Wc1'' row
//   pi(t,m) = 8a + 4t + r (t<2) ; 32 + 8a + 4(t-2) + r (t>=2)
// -> lane (c16,o) B1a outputs are HC[8o..8o+7] / HC[32+8o..+7] in register
//    order == B1b's B-fragment, so argb k-order stays unpermuted.
__device__ __forceinline__ int pi_row(int t, int m) {
  int a = m >> 2, r = m & 3;
  return (t < 2) ? (8 * a + 4 * t + r) : (32 + 8 * a + 4 * (t - 2) + r);
}

// ---------------- prep kernel: pack weight fragments into d_ws ----------------
// ws layout (uint4): a2 @0..127, c1a @128..383, k1a @384..639, a_rgb @640..767
// k1a unified B-fragment k-space: k=0 -> Wk1 row15 (sigma), k=1..15 -> Wk1 rows
// 0..14, k=16..18 -> 0 (dirs), k=19 -> bk1. a_rgb: channel c at A-row 4c.
__global__ void prep_kernel(fpp Wd2, fpp Wc1, fpp Wk1, fpp Wc2, fpp bc1, fpp bk1,
                            uint4* ws) {
  const int lane = threadIdx.x & 63;
  const int c16 = lane & 15, o = lane >> 4;
  uint t[4];
#pragma unroll
  for (int kt = 0; kt < 2; kt++) {
#pragma unroll
    for (int q = 0; q < 4; q++) {
      float w0 = Wd2[(32 * kt + 8 * o + 2 * q) * 16 + c16];
      float w1 = Wd2[(32 * kt + 8 * o + 2 * q + 1) * 16 + c16];
      t[q] = ((uint)(unsigned short)f2bf(w1) << 16) | (uint)(unsigned short)f2bf(w0);
    }
    ws[lane * 2 + kt] = make_uint4(t[0], t[1], t[2], t[3]);
  }
#pragma unroll
  for (int ht = 0; ht < 4; ht++) {
    uint tc[4], tk[4];
    const int hc_ = pi_row(ht, c16);     // pi-permuted row for c1a
    const int hk_ = 16 * ht + c16;       // original row for k1a
#pragma unroll
    for (int q = 0; q < 4; q++) {
      uint pc = 0, pkk = 0;
#pragma unroll
      for (int half = 0; half < 2; half++) {
        int k = 8 * o + 2 * q + half;
        float wc = 0.f, wk = 0.f;
        if (k >= 1 && k <= 15) wc = Wc1[(k + 2) * 64 + hc_];
        else if (k >= 16 && k <= 18) wc = Wc1[(k - 16) * 64 + hc_];
        else if (k == 19) wc = bc1[hc_];                  // bias row
        if (k == 0) wk = Wk1[15 * 64 + hk_];              // sigma row
        else if (k <= 15) wk = Wk1[(k - 1) * 64 + hk_];   // geo rows
        else if (k == 19) wk = bk1[hk_];                  // unified bias row
        pc  |= (uint)(unsigned short)f2bf(wc) << (16 * half);
        pkk |= (uint)(unsigned short)f2bf(wk) << (16 * half);
      }
      tc[q] = pc; tk[q] = pkk;
    }
    ws[128 + lane * 4 + ht] = make_uint4(tc[0], tc[1], tc[2], tc[3]);
    ws[384 + lane * 4 + ht] = make_uint4(tk[0], tk[1], tk[2], tk[3]);
  }
  // a_rgb: channel c at A-row 4c: c16==0 -> ch0, c16==4 -> ch1, c16==8 -> ch2
#pragma unroll
  for (int kt = 0; kt < 2; kt++) {
#pragma unroll
    for (int q = 0; q < 4; q++) {
      uint p = 0;
#pragma unroll
      for (int half = 0; half < 2; half++) {
        int h = 32 * kt + 8 * o + 2 * q + half;
        float w = 0.f;
        if (c16 == 0)      w = Wc2[h * 3 + 0];
        else if (c16 == 4) w = Wc2[h * 3 + 1];
        else if (c16 == 8) w = Wc2[h * 3 + 2];
        p |= (uint)(unsigned short)f2bf(w) << (16 * half);
      }
      t[q] = p;
    }
    ws[640 + lane * 2 + kt] = make_uint4(t[0], t[1], t[2], t[3]);
  }
}

// One ray per 64-thread block. Phase-2 weights (c1a/k1a/argb) are loaded AFTER
// the scan (behind a memory fence) so phase-1's register peak excludes them:
// on gfx950 the unified VGPR/AGPR file was the occupancy pin (~2.6 waves/SIMD
// at ~190 total regs across R5 AND R6 despite LDS dropping 4x).
template <bool PREP>
__global__ __launch_bounds__(64, 4) void nerf_kernel(
    fpp rays_o, fpp rays_d, fpp dnorms,
    fpp Wd1, fpp bd1, fpp Wd2, fpp bd2,
    fpp Wc1, fpp bc1, fpp Wc2, fpp bc2,
    fpp Wk1, fpp bk1, fpp Wk2, fpp bk2,
    const uint4* wsp, float* out)
{
  __shared__ short  geoA[256][8];   // cols 0-7 (sigma,geo0-6)
  __shared__ short  geoB[256][8];   // cols 8-15 (geo7-14)
  __shared__ float  tmp[256];       // phase1: sigma; scan onward: wm
  __shared__ i32x4  slots4[2];      // 0 = dirs+bias, 1 = zeros

  const int lane = threadIdx.x & 63;
  const int c16 = lane & 15, o = lane >> 4;
  const int ray = blockIdx.x;

  // ---------------- ray setup ----------------
  const float ox = rays_o[ray * 3 + 0], oy = rays_o[ray * 3 + 1], oz = rays_o[ray * 3 + 2];
  const float dx = rays_d[ray * 3 + 0], dy = rays_d[ray * 3 + 1], dz = rays_d[ray * 3 + 2];
  const float dn = dnorms[ray];
  const float ixr = 1.f / dx, iyr = 1.f / dy, izr = 1.f / dz;
  float t1x = (-1.f - ox) * ixr, t2x = (1.f - ox) * ixr;
  float t1y = (-1.f - oy) * iyr, t2y = (1.f - oy) * iyr;
  float t1z = (-1.f - oz) * izr, t2z = (1.f - oz) * izr;
  float nearv = fmaxf(fmaxf(fminf(t1x, t2x), fminf(t1y, t2y)), fminf(t1z, t2z));
  nearv = fmaxf(nearv, 0.2f);
  float farv = fminf(fminf(fmaxf(t1x, t2x), fmaxf(t1y, t2y)), fmaxf(t1z, t2z));
  farv = fmaxf(farv, nearv + 0.0001f);
  const float span = farv - nearv;

  // ---------------- phase-1 weight fragments ONLY (a2) ----------------
  bf16x8 a2[2];
  if (PREP) {
#pragma unroll
    for (int kt = 0; kt < 2; kt++)
      a2[kt] = __builtin_bit_cast(bf16x8, wsp[lane * 2 + kt]);
  } else {
#pragma unroll
    for (int kt = 0; kt < 2; kt++)
#pragma unroll
      for (int j = 0; j < 8; j++)
        a2[kt][j] = f2bf(Wd2[(32 * kt + 8 * o + j) * 16 + c16]);
  }

  // A1 linearized + per-lane constants
  float p1[16], q1[16];
#pragma unroll
  for (int kt = 0; kt < 2; kt++)
#pragma unroll
    for (int j = 0; j < 8; j++) {
      int h = 32 * kt + 8 * o + j;
      float w0 = Wd1[h], w1 = Wd1[64 + h], w2 = Wd1[128 + h];
      p1[8 * kt + j] = fmaf(w0, ox, fmaf(w1, oy, fmaf(w2, oz, bd1[h])));
      q1[8 * kt + j] = fmaf(w0, dx, fmaf(w1, dy, w2 * dz));
    }
  f32x4 bd2v = {bd2[4 * o], bd2[4 * o + 1], bd2[4 * o + 2], bd2[4 * o + 3]};
  const f32x4 zacc = {0.f, 0.f, 0.f, 0.f};

  // ================ PHASE 1: density MLP ====================================
  // unified geo write pointer (o<2 -> geoA cols 4o, o>=2 -> geoB cols 4(o-2))
  short* gws = ((o < 2) ? &geoA[0][4 * o] : &geoB[0][4 * (o - 2)]) + c16 * 8;
  float* tpw = &tmp[c16];
  float zt = nearv + span * ((float)c16 * (1.f / 255.f));
  const float ztstep = span * (16.f / 255.f);
#pragma unroll 1
  for (int mt = 0; mt < 16; mt++) {
    bf16x8 h1f[2];
#pragma unroll
    for (int kt = 0; kt < 2; kt++) {
      i32x4 tv;
#pragma unroll
      for (int q = 0; q < 4; q++) {
        float a = fmaxf(fmaf(q1[8 * kt + 2 * q],     zt, p1[8 * kt + 2 * q]),     0.f);
        float b = fmaxf(fmaf(q1[8 * kt + 2 * q + 1], zt, p1[8 * kt + 2 * q + 1]), 0.f);
        tv[q] = cvtpk(a, b);          // inputs are fmaxf outputs: hazard-safe
      }
      h1f[kt] = __builtin_bit_cast(bf16x8, tv);
    }
    f32x4 acc = bd2v;
    acc = MFMA(a2[0], h1f[0], acc);
    acc = MFMA(a2[1], h1f[1], acc);
    float sgm = __expf(acc[0]);                    // valid on o==0
    i32x2 pkv;
    pkv[0] = pkperm((o == 0) ? sgm : acc[0], acc[1]);  // 3-op pack, hazard-safe
    pkv[1] = pkperm(acc[2], acc[3]);
    *(i32x2*)gws = pkv;
    if (o == 0) *tpw = sgm;
    gws += 128; tpw += 16; zt += ztstep;
  }

  // ================ transmittance scan (t-layout fp32) =======================
  float z[4], wm[4];
  float ws, swz, depth, var, cx, cy, cz;
  __syncthreads();                                 // single-wave: near-free
  {
    f32x4 sgv = *(f32x4*)&tmp[lane * 4];
    float alpha[4], v[4], m[4];
#pragma unroll
    for (int i = 0; i < 4; i++) {
      int t = lane * 4 + i;
      z[i] = nearv + span * ((float)t * (1.f / 255.f));
      float delta = (t < 255) ? span * (1.f / 255.f) : span * (1.f / 256.f);
      alpha[i] = 1.f - __expf(-delta * sgv[i]);
      v[i] = 1.f - alpha[i] + 1e-15f;
    }
    m[0] = 1.f; m[1] = v[0]; m[2] = m[1] * v[1]; m[3] = m[2] * v[2];
    float ip = m[3] * v[3];
#pragma unroll
    for (int off = 1; off < 64; off <<= 1) {
      float u = __shfl_up(ip, off, 64);
      if (lane >= off) ip *= u;
    }
    float E = __shfl_up(ip, 1, 64);
    if (lane == 0) E = 1.f;
    ws = 0.f; swz = 0.f; cx = 0.f; cy = 0.f; cz = 0.f;
#pragma unroll
    for (int i = 0; i < 4; i++) {
      float w = alpha[i] * (E * m[i]);
      wm[i] = (w > 0.0001f) ? w : 0.f;
      ws += wm[i];
      swz = fmaf(wm[i], z[i], swz);
      float xc = fminf(fmaxf(fmaf(dx, z[i], ox), -1.f), 1.f);
      float yc = fminf(fmaxf(fmaf(dy, z[i], oy), -1.f), 1.f);
      float zc = fminf(fmaxf(fmaf(dz, z[i], oz), -1.f), 1.f);
      cx = fmaf(wm[i], xc, cx); cy = fmaf(wm[i], yc, cy); cz = fmaf(wm[i], zc, cz);
    }
    f32x4 wv4 = {wm[0], wm[1], wm[2], wm[3]};
    *(f32x4*)&tmp[lane * 4] = wv4;                 // overwrite sigma with wm
    ws = waveAllSum(ws); swz = waveAllSum(swz);
    cx = waveAllSum(cx); cy = waveAllSum(cy); cz = waveAllSum(cz);
    depth = swz / dn;
    var = 0.f;
#pragma unroll
    for (int i = 0; i < 4; i++) {
      float dd = depth - z[i] / dn;
      var = fmaf(wm[i], dd * dd, var);
    }
    var = waveAllSum(var);
  }
  if (lane == 0) {
    out[OFF_DEPTH + ray] = depth;
    out[OFF_VAR + ray]   = var;
    out[OFF_COORD + ray * 3 + 0] = cx;
    out[OFF_COORD + ray * 3 + 1] = cy;
    out[OFF_COORD + ray * 3 + 2] = cz;
    // per-wave constant B-fragment slots for o>=2 lanes
    i32x4 dv; dv[0] = pk2(dx, dy); dv[1] = pk2(dz, 1.f); dv[2] = 0; dv[3] = 0;
    slots4[0] = dv;                                // dirs(k16-18) + bias-one(k19)
    i32x4 zv = {0, 0, 0, 0};
    slots4[1] = zv;                                // zeros (o==3 rows)
  }
  __syncthreads();   // order slot/wm writes before phase-2 reads (1 wave: cheap)

  // ======== phase-2 weight fragments loaded HERE (shrinks phase-1 regs) ======
  asm volatile("" ::: "memory");   // fence: keep these loads below the scan
  bf16x8 c1a[4], k1a[4], argb[2];
  if (PREP) {
#pragma unroll
    for (int kt = 0; kt < 2; kt++)
      argb[kt] = __builtin_bit_cast(bf16x8, wsp[640 + lane * 2 + kt]);
#pragma unroll
    for (int ht = 0; ht < 4; ht++) {
      c1a[ht] = __builtin_bit_cast(bf16x8, wsp[128 + lane * 4 + ht]);
      k1a[ht] = __builtin_bit_cast(bf16x8, wsp[384 + lane * 4 + ht]);
    }
  } else {
#pragma unroll
    for (int kt = 0; kt < 2; kt++)
#pragma unroll
      for (int j = 0; j < 8; j++) {
        int h = 32 * kt + 8 * o + j;
        float w = 0.f;
        if (c16 == 0)      w = Wc2[h * 3 + 0];
        else if (c16 == 4) w = Wc2[h * 3 + 1];
        else if (c16 == 8) w = Wc2[h * 3 + 2];
        argb[kt][j] = f2bf(w);
      }
#pragma unroll
    for (int ht = 0; ht < 4; ht++) {
      const int hc_ = pi_row(ht, c16);
      const int hk_ = 16 * ht + c16;
#pragma unroll
      for (int j = 0; j < 8; j++) {
        int k = 8 * o + j;
        float wc = 0.f, wk = 0.f;
        if (k >= 1 && k <= 15) wc = Wc1[(k + 2) * 64 + hc_];
        else if (k >= 16 && k <= 18) wc = Wc1[(k - 16) * 64 + hc_];
        else if (k == 19) wc = bc1[hc_];
        if (k == 0) wk = Wk1[15 * 64 + hk_];
        else if (k <= 15) wk = Wk1[(k - 1) * 64 + hk_];
        else if (k == 19) wk = bk1[hk_];
        c1a[ht][j] = f2bf(wc);
        k1a[ht][j] = f2bf(wk);
      }
    }
  }
  f32x4 bc2i = {0.f, 0.f, 0.f, 0.f};
  if (o < 3) bc2i[0] = bc2[o];         // bias for channel o at D-row 4o

  // ================ PHASE 2: color + clip MLPs, fully MFMA ===================
  float ia = 0.f;                                  // image partial (channel o)
  float gp[4][4];
#pragma unroll
  for (int ht = 0; ht < 4; ht++)
#pragma unroll
    for (int r = 0; r < 4; r++) gp[ht][r] = 0.f;

  // single unified B-fragment stream (B1a color AND B2a clip share it)
  const short* pBs = ((o == 0) ? &geoA[0][0]
                    : (o == 1) ? &geoB[0][0]
                    : (o == 2) ? (const short*)&slots4[0]
                               : (const short*)&slots4[1]);
  const int sstep = (o < 2) ? 8 : 0;               // shorts per sample row
  pBs += c16 * sstep;
  const int stepB = 16 * sstep;                    // shorts per mt tile
  const float* tpr = &tmp[c16];
  // rgbs pointer: lane (c16,o) owns sample s=mt*16+c16, channel o (o<3)
  float* rgbp = out + OFF_RGBS + (long)ray * 768 + c16 * 3 + o;

#pragma unroll 1
  for (int mt = 0; mt < 16; mt++) {
    const bf16x8 bfr = *(const bf16x8*)pBs;        // unified B-fragment
    const float wmv = *tpr;
    // ---- B1a: HC = Wc1''(pi-rows) @ CIN''; outputs lane-local in k-order ----
    i32x4 h0v, h1v;
#pragma unroll
    for (int ht = 0; ht < 4; ht++) {
      f32x4 hc = MFMA(c1a[ht], bfr, zacc);
      int u0 = cvtpk(fmaxf(hc[0], 0.f), fmaxf(hc[1], 0.f));  // fmaxf-filtered: safe
      int u1 = cvtpk(fmaxf(hc[2], 0.f), fmaxf(hc[3], 0.f));
      if (ht == 0)      { h0v[0] = u0; h0v[1] = u1; }
      else if (ht == 1) { h0v[2] = u0; h0v[3] = u1; }
      else if (ht == 2) { h1v[0] = u0; h1v[1] = u1; }
      else              { h1v[2] = u0; h1v[3] = u1; }
    }
    // ---- B1b: rgb = Wc2^T @ relu(HC); channel o at D-row 4o -> racc[0] ----
    f32x4 racc = bc2i;
    racc = MFMA(argb[0], __builtin_bit_cast(bf16x8, h0v), racc);
    racc = MFMA(argb[1], __builtin_bit_cast(bf16x8, h1v), racc);
    // spread-channel epilogue: every lane handles ONE (sample,channel)
    {
      float sv = __builtin_amdgcn_rcpf(1.f + __expf(-racc[0]));
      sv = (wmv > 0.f) ? sv : 0.f;
      if (o < 3) *rgbp = sv;
      ia = fmaf(wmv, sv, ia);                      // channel-o partial
    }
    // ---- B2a: HK = Wk1''(unified-k) @ same bfr ----
#pragma unroll
    for (int ht = 0; ht < 4; ht++) {
      f32x4 hk = MFMA(k1a[ht], bfr, zacc);
#pragma unroll
      for (int r = 0; r < 4; r++)
        gp[ht][r] = fmaf(wmv, fmaxf(hk[r], 0.f), gp[ht][r]);
    }
    pBs += stepB; tpr += 16; rgbp += 48;
  }

  // image: reduce channel-o partial over c16 (within each 16-lane group)
  ia += __shfl_xor(ia, 1, 64); ia += __shfl_xor(ia, 2, 64);
  ia += __shfl_xor(ia, 4, 64); ia += __shfl_xor(ia, 8, 64);
  if (c16 == 0 && o < 3) out[OFF_IMG + ray * 3 + o] = ia + (1.f - ws);

  // ---- B2b: reduce g over samples, then clip = g @ Wk2 + ws*bk2 ----
#pragma unroll
  for (int ht = 0; ht < 4; ht++)
#pragma unroll
    for (int r = 0; r < 4; r++) {
      float g = gp[ht][r];
      g += __shfl_xor(g, 1, 64); g += __shfl_xor(g, 2, 64);
      g += __shfl_xor(g, 4, 64); g += __shfl_xor(g, 8, 64);
      gp[ht][r] = g;                 // g[h], h = 16*ht + 4*o + r
    }
  {
    const int k2 = 2 * c16;
    const float2* w2 = (const float2*)Wk2;   // [h][16] float2 pairs
    float cp0 = 0.f, cp1 = 0.f;
#pragma unroll
    for (int ht = 0; ht < 4; ht++)
#pragma unroll
      for (int r = 0; r < 4; r++) {
        int h = 16 * ht + 4 * o + r;
        float2 wv = w2[h * 16 + c16];
        cp0 = fmaf(gp[ht][r], wv.x, cp0);
        cp1 = fmaf(gp[ht][r], wv.y, cp1);
      }
    cp0 += __shfl_xor(cp0, 16, 64); cp0 += __shfl_xor(cp0, 32, 64);
    cp1 += __shfl_xor(cp1, 16, 64); cp1 += __shfl_xor(cp1, 32, 64);
    cp0 = fmaf(ws, bk2[k2], cp0);
    cp1 = fmaf(ws, bk2[k2 + 1], cp1);
    if (lane < 16) {
      out[OFF_CLIP + ray * 32 + k2]     = cp0;
      out[OFF_CLIP + ray * 32 + k2 + 1] = cp1;
    }
  }
}

extern "C" void kernel_launch(void* const* d_in, const int* in_sizes, int n_in,
                              void* d_out, int out_size, void* d_ws, size_t ws_size,
                              hipStream_t stream) {
  const bool prep = (ws_size >= 12288);
  if (prep) {
    prep_kernel<<<1, 64, 0, stream>>>((fpp)d_in[5], (fpp)d_in[7], (fpp)d_in[11],
                                      (fpp)d_in[9], (fpp)d_in[8], (fpp)d_in[12],
                                      (uint4*)d_ws);
    nerf_kernel<true><<<NRAYS, 64, 0, stream>>>(
        (fpp)d_in[0], (fpp)d_in[1], (fpp)d_in[2],
        (fpp)d_in[3], (fpp)d_in[4], (fpp)d_in[5], (fpp)d_in[6],
        (fpp)d_in[7], (fpp)d_in[8], (fpp)d_in[9], (fpp)d_in[10],
        (fpp)d_in[11], (fpp)d_in[12], (fpp)d_in[13], (fpp)d_in[14],
        (const uint4*)d_ws, (float*)d_out);
  } else {
    nerf_kernel<false><<<NRAYS, 64, 0, stream>>>(
        (fpp)d_in[0], (fpp)d_in[1], (fpp)d_in[2],
        (fpp)d_in[3], (fpp)d_in[4], (fpp)d_in[5], (fpp)d_in[6],
        (fpp)d_in[7], (fpp)d_in[8], (fpp)d_in[9], (fpp)d_in[10],
        (fpp)d_in[11], (fpp)d_in[12], (fpp)d_in[13], (fpp)d_in[14],
        (const uint4*)d_ws, (float*)d_out);
  }
}

// Round 8
// 147.407 us; speedup vs baseline: 1.0179x; 1.0179x over previous
//
#include <hip/hip_runtime.h>

#define NRAYS 8192
typedef const float* fpp;
typedef unsigned int uint;

typedef short bf16x8 __attribute__((ext_vector_type(8)));
typedef int   i32x4  __attribute__((ext_vector_type(4)));
typedef int   i32x2  __attribute__((ext_vector_type(2)));
typedef float f32x4  __attribute__((ext_vector_type(4)));

__device__ __forceinline__ uint bfbits(float f) {          // RNE fp32->bf16 bits
  uint u = __float_as_uint(f);
  return (u + 0x7FFFu + ((u >> 16) & 1u)) >> 16;
}
__device__ __forceinline__ short f2bf(float f) { return (short)bfbits(f); }
// RNE pack (prep/setup only)
__device__ __forceinline__ int pk2(float a, float b) {
  return (int)(bfbits(a) | (bfbits(b) << 16));
}
// 3-op perm pack (round-half-up, R0-baseline-proven for the geo store):
// low short = bf16(a), high short = bf16(b). Pure C++ ops -> hazard-safe on accs.
__device__ __forceinline__ int pkperm(float a, float b) {
  return (int)__builtin_amdgcn_perm(__float_as_uint(b) + 0x8000u,
                                    __float_as_uint(a) + 0x8000u, 0x07060302u);
}
// single-instruction packed convert — ONLY for inputs already filtered through
// a compiler-visible VALU op (e.g. fmaxf); raw MFMA accs must NOT feed this (R3).
__device__ __forceinline__ int cvtpk(float a, float b) {
  int r;
  asm("v_cvt_pk_bf16_f32 %0, %1, %2" : "=v"(r) : "v"(a), "v"(b));
  return r;
}
__device__ __forceinline__ f32x4 MFMA(bf16x8 a, bf16x8 b, f32x4 c) {
  return __builtin_amdgcn_mfma_f32_16x16x32_bf16(a, b, c, 0, 0, 0);
}
__device__ __forceinline__ float waveAllSum(float v) {
#pragma unroll
  for (int off = 32; off > 0; off >>= 1) v += __shfl_xor(v, off, 64);
  return v;
}

// output layout (flat fp32): image[8192,3]@0 depth@24576 dvar@32768 coord@40960
// rgbs[8192,256,3]@65536 clip[8192,32]@6356992
#define OFF_IMG   0
#define OFF_DEPTH 24576
#define OFF_VAR   32768
#define OFF_COORD 40960
#define OFF_RGBS  65536
#define OFF_CLIP  6356992

// c1a M-row permutation: tile t, in-tile row m (=4a+r) sources Wc1'' row
//   pi(t,m) = 8a + 4t + r (t<2) ; 32 + 8a + 4(t-2) + r (t>=2)
// -> lane (c16,o) B1a outputs are HC[8o..8o+7] / HC[32+8o..+7] in register
//    order == B1b's B-fragment, so argb k-order stays unpermuted.
__device__ __forceinline__ int pi_row(int t, int m) {
  int a = m >> 2, r = m & 3;
  return (t < 2) ? (8 * a + 4 * t + r) : (32 + 8 * a + 4 * (t - 2) + r);
}

// ---------------- prep kernel: pack weight fragments into d_ws ----------------
// ws layout (uint4): a2 @0..127, c1a @128..383, k1a @384..639, a_rgb @640..767
// k1a unified B-fragment k-space: k=0 -> Wk1 row15 (sigma), k=1..15 -> Wk1 rows
// 0..14, k=16..18 -> 0 (dirs), k=19 -> bk1. a_rgb: channel c at A-row 4c.
__global__ void prep_kernel(fpp Wd2, fpp Wc1, fpp Wk1, fpp Wc2, fpp bc1, fpp bk1,
                            uint4* ws) {
  const int lane = threadIdx.x & 63;
  const int c16 = lane & 15, o = lane >> 4;
  uint t[4];
#pragma unroll
  for (int kt = 0; kt < 2; kt++) {
#pragma unroll
    for (int q = 0; q < 4; q++) {
      float w0 = Wd2[(32 * kt + 8 * o + 2 * q) * 16 + c16];
      float w1 = Wd2[(32 * kt + 8 * o + 2 * q + 1) * 16 + c16];
      t[q] = ((uint)(unsigned short)f2bf(w1) << 16) | (uint)(unsigned short)f2bf(w0);
    }
    ws[lane * 2 + kt] = make_uint4(t[0], t[1], t[2], t[3]);
  }
#pragma unroll
  for (int ht = 0; ht < 4; ht++) {
    uint tc[4], tk[4];
    const int hc_ = pi_row(ht, c16);     // pi-permuted row for c1a
    const int hk_ = 16 * ht + c16;       // original row for k1a
#pragma unroll
    for (int q = 0; q < 4; q++) {
      uint pc = 0, pkk = 0;
#pragma unroll
      for (int half = 0; half < 2; half++) {
        int k = 8 * o + 2 * q + half;
        float wc = 0.f, wk = 0.f;
        if (k >= 1 && k <= 15) wc = Wc1[(k + 2) * 64 + hc_];
        else if (k >= 16 && k <= 18) wc = Wc1[(k - 16) * 64 + hc_];
        else if (k == 19) wc = bc1[hc_];                  // bias row
        if (k == 0) wk = Wk1[15 * 64 + hk_];              // sigma row
        else if (k <= 15) wk = Wk1[(k - 1) * 64 + hk_];   // geo rows
        else if (k == 19) wk = bk1[hk_];                  // unified bias row
        pc  |= (uint)(unsigned short)f2bf(wc) << (16 * half);
        pkk |= (uint)(unsigned short)f2bf(wk) << (16 * half);
      }
      tc[q] = pc; tk[q] = pkk;
    }
    ws[128 + lane * 4 + ht] = make_uint4(tc[0], tc[1], tc[2], tc[3]);
    ws[384 + lane * 4 + ht] = make_uint4(tk[0], tk[1], tk[2], tk[3]);
  }
  // a_rgb: channel c at A-row 4c: c16==0 -> ch0, c16==4 -> ch1, c16==8 -> ch2
#pragma unroll
  for (int kt = 0; kt < 2; kt++) {
#pragma unroll
    for (int q = 0; q < 4; q++) {
      uint p = 0;
#pragma unroll
      for (int half = 0; half < 2; half++) {
        int h = 32 * kt + 8 * o + 2 * q + half;
        float w = 0.f;
        if (c16 == 0)      w = Wc2[h * 3 + 0];
        else if (c16 == 4) w = Wc2[h * 3 + 1];
        else if (c16 == 8) w = Wc2[h * 3 + 2];
        p |= (uint)(unsigned short)f2bf(w) << (16 * half);
      }
      t[q] = p;
    }
    ws[640 + lane * 2 + kt] = make_uint4(t[0], t[1], t[2], t[3]);
  }
}

// One ray per 64-thread block. __launch_bounds__(64, 3): VGPR cap 170 —
// enough for the ~90-120 live peak WITHOUT spilling. R5-R7 all pinned at
// ~10 waves/CU regardless of LDS/block-size/VGPR_Count; reported VGPR (48-64)
// was far below the live-state audit (~90+), i.e. the allocator was spilling
// to scratch, and per-wave scratch backing was pinning occupancy + latency.
template <bool PREP>
__global__ __launch_bounds__(64, 3) void nerf_kernel(
    fpp rays_o, fpp rays_d, fpp dnorms,
    fpp Wd1, fpp bd1, fpp Wd2, fpp bd2,
    fpp Wc1, fpp bc1, fpp Wc2, fpp bc2,
    fpp Wk1, fpp bk1, fpp Wk2, fpp bk2,
    const uint4* wsp, float* out)
{
  __shared__ short  geoA[256][8];   // cols 0-7 (sigma,geo0-6)
  __shared__ short  geoB[256][8];   // cols 8-15 (geo7-14)
  __shared__ float  tmp[256];       // phase1: sigma; scan onward: wm
  __shared__ i32x4  slots4[2];      // 0 = dirs+bias, 1 = zeros

  const int lane = threadIdx.x & 63;
  const int c16 = lane & 15, o = lane >> 4;
  const int ray = blockIdx.x;

  // ---------------- ray setup ----------------
  const float ox = rays_o[ray * 3 + 0], oy = rays_o[ray * 3 + 1], oz = rays_o[ray * 3 + 2];
  const float dx = rays_d[ray * 3 + 0], dy = rays_d[ray * 3 + 1], dz = rays_d[ray * 3 + 2];
  const float dn = dnorms[ray];
  const float ixr = 1.f / dx, iyr = 1.f / dy, izr = 1.f / dz;
  float t1x = (-1.f - ox) * ixr, t2x = (1.f - ox) * ixr;
  float t1y = (-1.f - oy) * iyr, t2y = (1.f - oy) * iyr;
  float t1z = (-1.f - oz) * izr, t2z = (1.f - oz) * izr;
  float nearv = fmaxf(fmaxf(fminf(t1x, t2x), fminf(t1y, t2y)), fminf(t1z, t2z));
  nearv = fmaxf(nearv, 0.2f);
  float farv = fminf(fminf(fmaxf(t1x, t2x), fmaxf(t1y, t2y)), fmaxf(t1z, t2z));
  farv = fmaxf(farv, nearv + 0.0001f);
  const float span = farv - nearv;

  // ---------------- weight fragments (all up front; R7 sink regressed) -------
  bf16x8 a2[2], c1a[4], k1a[4], argb[2];
  if (PREP) {
#pragma unroll
    for (int kt = 0; kt < 2; kt++) {
      a2[kt]   = __builtin_bit_cast(bf16x8, wsp[lane * 2 + kt]);
      argb[kt] = __builtin_bit_cast(bf16x8, wsp[640 + lane * 2 + kt]);
    }
#pragma unroll
    for (int ht = 0; ht < 4; ht++) {
      c1a[ht] = __builtin_bit_cast(bf16x8, wsp[128 + lane * 4 + ht]);
      k1a[ht] = __builtin_bit_cast(bf16x8, wsp[384 + lane * 4 + ht]);
    }
  } else {
#pragma unroll
    for (int kt = 0; kt < 2; kt++)
#pragma unroll
      for (int j = 0; j < 8; j++) {
        a2[kt][j] = f2bf(Wd2[(32 * kt + 8 * o + j) * 16 + c16]);
        int h = 32 * kt + 8 * o + j;
        float w = 0.f;
        if (c16 == 0)      w = Wc2[h * 3 + 0];
        else if (c16 == 4) w = Wc2[h * 3 + 1];
        else if (c16 == 8) w = Wc2[h * 3 + 2];
        argb[kt][j] = f2bf(w);
      }
#pragma unroll
    for (int ht = 0; ht < 4; ht++) {
      const int hc_ = pi_row(ht, c16);
      const int hk_ = 16 * ht + c16;
#pragma unroll
      for (int j = 0; j < 8; j++) {
        int k = 8 * o + j;
        float wc = 0.f, wk = 0.f;
        if (k >= 1 && k <= 15) wc = Wc1[(k + 2) * 64 + hc_];
        else if (k >= 16 && k <= 18) wc = Wc1[(k - 16) * 64 + hc_];
        else if (k == 19) wc = bc1[hc_];
        if (k == 0) wk = Wk1[15 * 64 + hk_];
        else if (k <= 15) wk = Wk1[(k - 1) * 64 + hk_];
        else if (k == 19) wk = bk1[hk_];
        c1a[ht][j] = f2bf(wc);
        k1a[ht][j] = f2bf(wk);
      }
    }
  }

  // A1 linearized + per-lane constants
  float p1[16], q1[16];
#pragma unroll
  for (int kt = 0; kt < 2; kt++)
#pragma unroll
    for (int j = 0; j < 8; j++) {
      int h = 32 * kt + 8 * o + j;
      float w0 = Wd1[h], w1 = Wd1[64 + h], w2 = Wd1[128 + h];
      p1[8 * kt + j] = fmaf(w0, ox, fmaf(w1, oy, fmaf(w2, oz, bd1[h])));
      q1[8 * kt + j] = fmaf(w0, dx, fmaf(w1, dy, w2 * dz));
    }
  f32x4 bd2v = {bd2[4 * o], bd2[4 * o + 1], bd2[4 * o + 2], bd2[4 * o + 3]};
  f32x4 bc2i = {0.f, 0.f, 0.f, 0.f};
  if (o < 3) bc2i[0] = bc2[o];         // bias for channel o at D-row 4o
  const f32x4 zacc = {0.f, 0.f, 0.f, 0.f};

  // ================ PHASE 1: density MLP ====================================
  // unified geo write pointer (o<2 -> geoA cols 4o, o>=2 -> geoB cols 4(o-2))
  short* gws = ((o < 2) ? &geoA[0][4 * o] : &geoB[0][4 * (o - 2)]) + c16 * 8;
  float* tpw = &tmp[c16];
  float zt = nearv + span * ((float)c16 * (1.f / 255.f));
  const float ztstep = span * (16.f / 255.f);
#pragma unroll 1
  for (int mt = 0; mt < 16; mt++) {
    bf16x8 h1f[2];
#pragma unroll
    for (int kt = 0; kt < 2; kt++) {
      i32x4 tv;
#pragma unroll
      for (int q = 0; q < 4; q++) {
        float a = fmaxf(fmaf(q1[8 * kt + 2 * q],     zt, p1[8 * kt + 2 * q]),     0.f);
        float b = fmaxf(fmaf(q1[8 * kt + 2 * q + 1], zt, p1[8 * kt + 2 * q + 1]), 0.f);
        tv[q] = cvtpk(a, b);          // inputs are fmaxf outputs: hazard-safe
      }
      h1f[kt] = __builtin_bit_cast(bf16x8, tv);
    }
    f32x4 acc = bd2v;
    acc = MFMA(a2[0], h1f[0], acc);
    acc = MFMA(a2[1], h1f[1], acc);
    float sgm = __expf(acc[0]);                    // valid on o==0
    i32x2 pkv;
    pkv[0] = pkperm((o == 0) ? sgm : acc[0], acc[1]);  // 3-op pack, hazard-safe
    pkv[1] = pkperm(acc[2], acc[3]);
    *(i32x2*)gws = pkv;
    if (o == 0) *tpw = sgm;
    gws += 128; tpw += 16; zt += ztstep;
  }

  // ================ transmittance scan (t-layout fp32) =======================
  float z[4], wm[4];
  float ws, swz, depth, var, cx, cy, cz;
  __syncthreads();                                 // single-wave: near-free
  {
    f32x4 sgv = *(f32x4*)&tmp[lane * 4];
    float alpha[4], v[4], m[4];
#pragma unroll
    for (int i = 0; i < 4; i++) {
      int t = lane * 4 + i;
      z[i] = nearv + span * ((float)t * (1.f / 255.f));
      float delta = (t < 255) ? span * (1.f / 255.f) : span * (1.f / 256.f);
      alpha[i] = 1.f - __expf(-delta * sgv[i]);
      v[i] = 1.f - alpha[i] + 1e-15f;
    }
    m[0] = 1.f; m[1] = v[0]; m[2] = m[1] * v[1]; m[3] = m[2] * v[2];
    float ip = m[3] * v[3];
#pragma unroll
    for (int off = 1; off < 64; off <<= 1) {
      float u = __shfl_up(ip, off, 64);
      if (lane >= off) ip *= u;
    }
    float E = __shfl_up(ip, 1, 64);
    if (lane == 0) E = 1.f;
    ws = 0.f; swz = 0.f; cx = 0.f; cy = 0.f; cz = 0.f;
#pragma unroll
    for (int i = 0; i < 4; i++) {
      float w = alpha[i] * (E * m[i]);
      wm[i] = (w > 0.0001f) ? w : 0.f;
      ws += wm[i];
      swz = fmaf(wm[i], z[i], swz);
      float xc = fminf(fmaxf(fmaf(dx, z[i], ox), -1.f), 1.f);
      float yc = fminf(fmaxf(fmaf(dy, z[i], oy), -1.f), 1.f);
      float zc = fminf(fmaxf(fmaf(dz, z[i], oz), -1.f), 1.f);
      cx = fmaf(wm[i], xc, cx); cy = fmaf(wm[i], yc, cy); cz = fmaf(wm[i], zc, cz);
    }
    f32x4 wv4 = {wm[0], wm[1], wm[2], wm[3]};
    *(f32x4*)&tmp[lane * 4] = wv4;                 // overwrite sigma with wm
    ws = waveAllSum(ws); swz = waveAllSum(swz);
    cx = waveAllSum(cx); cy = waveAllSum(cy); cz = waveAllSum(cz);
    depth = swz / dn;
    var = 0.f;
#pragma unroll
    for (int i = 0; i < 4; i++) {
      float dd = depth - z[i] / dn;
      var = fmaf(wm[i], dd * dd, var);
    }
    var = waveAllSum(var);
  }
  if (lane == 0) {
    out[OFF_DEPTH + ray] = depth;
    out[OFF_VAR + ray]   = var;
    out[OFF_COORD + ray * 3 + 0] = cx;
    out[OFF_COORD + ray * 3 + 1] = cy;
    out[OFF_COORD + ray * 3 + 2] = cz;
    // per-wave constant B-fragment slots for o>=2 lanes
    i32x4 dv; dv[0] = pk2(dx, dy); dv[1] = pk2(dz, 1.f); dv[2] = 0; dv[3] = 0;
    slots4[0] = dv;                                // dirs(k16-18) + bias-one(k19)
    i32x4 zv = {0, 0, 0, 0};
    slots4[1] = zv;                                // zeros (o==3 rows)
  }
  __syncthreads();   // order slot/wm writes before phase-2 reads (1 wave: cheap)

  // ================ PHASE 2: color + clip MLPs, fully MFMA ===================
  float ia = 0.f;                                  // image partial (channel o)
  float gp[4][4];
#pragma unroll
  for (int ht = 0; ht < 4; ht++)
#pragma unroll
    for (int r = 0; r < 4; r++) gp[ht][r] = 0.f;

  // single unified B-fragment stream (B1a color AND B2a clip share it)
  const short* pBs = ((o == 0) ? &geoA[0][0]
                    : (o == 1) ? &geoB[0][0]
                    : (o == 2) ? (const short*)&slots4[0]
                               : (const short*)&slots4[1]);
  const int sstep = (o < 2) ? 8 : 0;               // shorts per sample row
  pBs += c16 * sstep;
  const int stepB = 16 * sstep;                    // shorts per mt tile
  const float* tpr = &tmp[c16];
  // rgbs pointer: lane (c16,o) owns sample s=mt*16+c16, channel o (o<3)
  float* rgbp = out + OFF_RGBS + (long)ray * 768 + c16 * 3 + o;

#pragma unroll 1
  for (int mt = 0; mt < 16; mt++) {
    const bf16x8 bfr = *(const bf16x8*)pBs;        // unified B-fragment
    const float wmv = *tpr;
    // ---- B1a: HC = Wc1''(pi-rows) @ CIN''; outputs lane-local in k-order ----
    i32x4 h0v, h1v;
#pragma unroll
    for (int ht = 0; ht < 4; ht++) {
      f32x4 hc = MFMA(c1a[ht], bfr, zacc);
      int u0 = cvtpk(fmaxf(hc[0], 0.f), fmaxf(hc[1], 0.f));  // fmaxf-filtered: safe
      int u1 = cvtpk(fmaxf(hc[2], 0.f), fmaxf(hc[3], 0.f));
      if (ht == 0)      { h0v[0] = u0; h0v[1] = u1; }
      else if (ht == 1) { h0v[2] = u0; h0v[3] = u1; }
      else if (ht == 2) { h1v[0] = u0; h1v[1] = u1; }
      else              { h1v[2] = u0; h1v[3] = u1; }
    }
    // ---- B1b: rgb = Wc2^T @ relu(HC); channel o at D-row 4o -> racc[0] ----
    f32x4 racc = bc2i;
    racc = MFMA(argb[0], __builtin_bit_cast(bf16x8, h0v), racc);
    racc = MFMA(argb[1], __builtin_bit_cast(bf16x8, h1v), racc);
    // spread-channel epilogue: every lane handles ONE (sample,channel)
    {
      float sv = __builtin_amdgcn_rcpf(1.f + __expf(-racc[0]));
      sv = (wmv > 0.f) ? sv : 0.f;
      if (o < 3) *rgbp = sv;
      ia = fmaf(wmv, sv, ia);                      // channel-o partial
    }
    // ---- B2a: HK = Wk1''(unified-k) @ same bfr ----
#pragma unroll
    for (int ht = 0; ht < 4; ht++) {
      f32x4 hk = MFMA(k1a[ht], bfr, zacc);
#pragma unroll
      for (int r = 0; r < 4; r++)
        gp[ht][r] = fmaf(wmv, fmaxf(hk[r], 0.f), gp[ht][r]);
    }
    pBs += stepB; tpr += 16; rgbp += 48;
  }

  // image: reduce channel-o partial over c16 (within each 16-lane group)
  ia += __shfl_xor(ia, 1, 64); ia += __shfl_xor(ia, 2, 64);
  ia += __shfl_xor(ia, 4, 64); ia += __shfl_xor(ia, 8, 64);
  if (c16 == 0 && o < 3) out[OFF_IMG + ray * 3 + o] = ia + (1.f - ws);

  // ---- B2b: reduce g over samples, then clip = g @ Wk2 + ws*bk2 ----
#pragma unroll
  for (int ht = 0; ht < 4; ht++)
#pragma unroll
    for (int r = 0; r < 4; r++) {
      float g = gp[ht][r];
      g += __shfl_xor(g, 1, 64); g += __shfl_xor(g, 2, 64);
      g += __shfl_xor(g, 4, 64); g += __shfl_xor(g, 8, 64);
      gp[ht][r] = g;                 // g[h], h = 16*ht + 4*o + r
    }
  {
    const int k2 = 2 * c16;
    const float2* w2 = (const float2*)Wk2;   // [h][16] float2 pairs
    float cp0 = 0.f, cp1 = 0.f;
#pragma unroll
    for (int ht = 0; ht < 4; ht++)
#pragma unroll
      for (int r = 0; r < 4; r++) {
        int h = 16 * ht + 4 * o + r;
        float2 wv = w2[h * 16 + c16];
        cp0 = fmaf(gp[ht][r], wv.x, cp0);
        cp1 = fmaf(gp[ht][r], wv.y, cp1);
      }
    cp0 += __shfl_xor(cp0, 16, 64); cp0 += __shfl_xor(cp0, 32, 64);
    cp1 += __shfl_xor(cp1, 16, 64); cp1 += __shfl_xor(cp1, 32, 64);
    cp0 = fmaf(ws, bk2[k2], cp0);
    cp1 = fmaf(ws, bk2[k2 + 1], cp1);
    if (lane < 16) {
      out[OFF_CLIP + ray * 32 + k2]     = cp0;
      out[OFF_CLIP + ray * 32 + k2 + 1] = cp1;
    }
  }
}

extern "C" void kernel_launch(void* const* d_in, const int* in_sizes, int n_in,
                              void* d_out, int out_size, void* d_ws, size_t ws_size,
                              hipStream_t stream) {
  const bool prep = (ws_size >= 12288);
  if (prep) {
    prep_kernel<<<1, 64, 0, stream>>>((fpp)d_in[5], (fpp)d_in[7], (fpp)d_in[11],
                                      (fpp)d_in[9], (fpp)d_in[8], (fpp)d_in[12],
                                      (uint4*)d_ws);
    nerf_kernel<true><<<NRAYS, 64, 0, stream>>>(
        (fpp)d_in[0], (fpp)d_in[1], (fpp)d_in[2],
        (fpp)d_in[3], (fpp)d_in[4], (fpp)d_in[5], (fpp)d_in[6],
        (fpp)d_in[7], (fpp)d_in[8], (fpp)d_in[9], (fpp)d_in[10],
        (fpp)d_in[11], (fpp)d_in[12], (fpp)d_in[13], (fpp)d_in[14],
        (const uint4*)d_ws, (float*)d_out);
  } else {
    nerf_kernel<false><<<NRAYS, 64, 0, stream>>>(
        (fpp)d_in[0], (fpp)d_in[1], (fpp)d_in[2],
        (fpp)d_in[3], (fpp)d_in[4], (fpp)d_in[5], (fpp)d_in[6],
        (fpp)d_in[7], (fpp)d_in[8], (fpp)d_in[9], (fpp)d_in[10],
        (fpp)d_in[11], (fpp)d_in[12], (fpp)d_in[13], (fpp)d_in[14],
        (const uint4*)d_ws, (float*)d_out);
  }
}

// Round 9
// 146.400 us; speedup vs baseline: 1.0249x; 1.0069x over previous
//
#include <hip/hip_runtime.h>

#define NRAYS 8192
typedef const float* fpp;
typedef unsigned int uint;

typedef short bf16x8 __attribute__((ext_vector_type(8)));
typedef int   i32x4  __attribute__((ext_vector_type(4)));
typedef int   i32x2  __attribute__((ext_vector_type(2)));
typedef float f32x4  __attribute__((ext_vector_type(4)));

__device__ __forceinline__ uint bfbits(float f) {          // RNE fp32->bf16 bits
  uint u = __float_as_uint(f);
  return (u + 0x7FFFu + ((u >> 16) & 1u)) >> 16;
}
__device__ __forceinline__ short f2bf(float f) { return (short)bfbits(f); }
// RNE pack (prep/setup only)
__device__ __forceinline__ int pk2(float a, float b) {
  return (int)(bfbits(a) | (bfbits(b) << 16));
}
// 3-op perm pack (round-half-up, R0-baseline-proven for the geo store):
// low short = bf16(a), high short = bf16(b). Pure C++ ops -> hazard-safe on accs.
__device__ __forceinline__ int pkperm(float a, float b) {
  return (int)__builtin_amdgcn_perm(__float_as_uint(b) + 0x8000u,
                                    __float_as_uint(a) + 0x8000u, 0x07060302u);
}
// single-instruction packed convert — ONLY for inputs already filtered through
// a compiler-visible VALU op (e.g. fmaxf); raw MFMA accs must NOT feed this (R3).
__device__ __forceinline__ int cvtpk(float a, float b) {
  int r;
  asm("v_cvt_pk_bf16_f32 %0, %1, %2" : "=v"(r) : "v"(a), "v"(b));
  return r;
}
__device__ __forceinline__ f32x4 MFMA(bf16x8 a, bf16x8 b, f32x4 c) {
  return __builtin_amdgcn_mfma_f32_16x16x32_bf16(a, b, c, 0, 0, 0);
}
__device__ __forceinline__ float waveAllSum(float v) {
#pragma unroll
  for (int off = 32; off > 0; off >>= 1) v += __shfl_xor(v, off, 64);
  return v;
}

// output layout (flat fp32): image[8192,3]@0 depth@24576 dvar@32768 coord@40960
// rgbs[8192,256,3]@65536 clip[8192,32]@6356992
#define OFF_IMG   0
#define OFF_DEPTH 24576
#define OFF_VAR   32768
#define OFF_COORD 40960
#define OFF_RGBS  65536
#define OFF_CLIP  6356992

// c1a M-row permutation: tile t, in-tile row m (=4a+r) sources Wc1'' row
//   pi(t,m) = 8a + 4t + r (t<2) ; 32 + 8a + 4(t-2) + r (t>=2)
// -> lane (c16,o) B1a outputs are HC[8o..8o+7] / HC[32+8o..+7] in register
//    order == B1b's B-fragment, so argb k-order stays unpermuted.
__device__ __forceinline__ int pi_row(int t, int m) {
  int a = m >> 2, r = m & 3;
  return (t < 2) ? (8 * a + 4 * t + r) : (32 + 8 * a + 4 * (t - 2) + r);
}

// ---------------- prep kernel: pack weight fragments into d_ws ----------------
// ws layout (uint4): a2 @0..127, c1a @128..383, k1a @384..639, a_rgb @640..767
// k1a unified B-fragment k-space: k=0 -> Wk1 row15 (sigma), k=1..15 -> Wk1 rows
// 0..14, k=16..18 -> 0 (dirs), k=19 -> bk1. a_rgb: channel c at A-row 4c.
__global__ void prep_kernel(fpp Wd2, fpp Wc1, fpp Wk1, fpp Wc2, fpp bc1, fpp bk1,
                            uint4* ws) {
  const int lane = threadIdx.x & 63;
  const int c16 = lane & 15, o = lane >> 4;
  uint t[4];
#pragma unroll
  for (int kt = 0; kt < 2; kt++) {
#pragma unroll
    for (int q = 0; q < 4; q++) {
      float w0 = Wd2[(32 * kt + 8 * o + 2 * q) * 16 + c16];
      float w1 = Wd2[(32 * kt + 8 * o + 2 * q + 1) * 16 + c16];
      t[q] = ((uint)(unsigned short)f2bf(w1) << 16) | (uint)(unsigned short)f2bf(w0);
    }
    ws[lane * 2 + kt] = make_uint4(t[0], t[1], t[2], t[3]);
  }
#pragma unroll
  for (int ht = 0; ht < 4; ht++) {
    uint tc[4], tk[4];
    const int hc_ = pi_row(ht, c16);     // pi-permuted row for c1a
    const int hk_ = 16 * ht + c16;       // original row for k1a
#pragma unroll
    for (int q = 0; q < 4; q++) {
      uint pc = 0, pkk = 0;
#pragma unroll
      for (int half = 0; half < 2; half++) {
        int k = 8 * o + 2 * q + half;
        float wc = 0.f, wk = 0.f;
        if (k >= 1 && k <= 15) wc = Wc1[(k + 2) * 64 + hc_];
        else if (k >= 16 && k <= 18) wc = Wc1[(k - 16) * 64 + hc_];
        else if (k == 19) wc = bc1[hc_];                  // bias row
        if (k == 0) wk = Wk1[15 * 64 + hk_];              // sigma row
        else if (k <= 15) wk = Wk1[(k - 1) * 64 + hk_];   // geo rows
        else if (k == 19) wk = bk1[hk_];                  // unified bias row
        pc  |= (uint)(unsigned short)f2bf(wc) << (16 * half);
        pkk |= (uint)(unsigned short)f2bf(wk) << (16 * half);
      }
      tc[q] = pc; tk[q] = pkk;
    }
    ws[128 + lane * 4 + ht] = make_uint4(tc[0], tc[1], tc[2], tc[3]);
    ws[384 + lane * 4 + ht] = make_uint4(tk[0], tk[1], tk[2], tk[3]);
  }
  // a_rgb: channel c at A-row 4c: c16==0 -> ch0, c16==4 -> ch1, c16==8 -> ch2
#pragma unroll
  for (int kt = 0; kt < 2; kt++) {
#pragma unroll
    for (int q = 0; q < 4; q++) {
      uint p = 0;
#pragma unroll
      for (int half = 0; half < 2; half++) {
        int h = 32 * kt + 8 * o + 2 * q + half;
        float w = 0.f;
        if (c16 == 0)      w = Wc2[h * 3 + 0];
        else if (c16 == 4) w = Wc2[h * 3 + 1];
        else if (c16 == 8) w = Wc2[h * 3 + 2];
        p |= (uint)(unsigned short)f2bf(w) << (16 * half);
      }
      t[q] = p;
    }
    ws[640 + lane * 2 + kt] = make_uint4(t[0], t[1], t[2], t[3]);
  }
}

// One ray per 64-thread block. wm is staged TRANSPOSED (tmpT[c16][mt], padded
// row stride 20 floats: 16B-aligned rows, ~2-way banks = free) so phase 2 reads
// one f32x4 per 4 iterations instead of a 120-cycle ds_read_b32 every
// iteration. Phase 2 runs as 4 outer x 4 inner (inner fully unrolled ->
// compile-time wmq index, rule-#20 safe, real cross-iteration ILP).
template <bool PREP>
__global__ __launch_bounds__(64, 3) void nerf_kernel(
    fpp rays_o, fpp rays_d, fpp dnorms,
    fpp Wd1, fpp bd1, fpp Wd2, fpp bd2,
    fpp Wc1, fpp bc1, fpp Wc2, fpp bc2,
    fpp Wk1, fpp bk1, fpp Wk2, fpp bk2,
    const uint4* wsp, float* out)
{
  __shared__ short  geoA[256][8];   // cols 0-7 (sigma,geo0-6)
  __shared__ short  geoB[256][8];   // cols 8-15 (geo7-14)
  __shared__ float  tmp[256];       // phase1 sigma (t-layout)
  __shared__ __attribute__((aligned(16))) float tmpT[16][20];  // wm transposed
  __shared__ i32x4  slots4[2];      // 0 = dirs+bias, 1 = zeros

  const int lane = threadIdx.x & 63;
  const int c16 = lane & 15, o = lane >> 4;
  const int ray = blockIdx.x;

  // ---------------- ray setup ----------------
  const float ox = rays_o[ray * 3 + 0], oy = rays_o[ray * 3 + 1], oz = rays_o[ray * 3 + 2];
  const float dx = rays_d[ray * 3 + 0], dy = rays_d[ray * 3 + 1], dz = rays_d[ray * 3 + 2];
  const float dn = dnorms[ray];
  const float ixr = 1.f / dx, iyr = 1.f / dy, izr = 1.f / dz;
  float t1x = (-1.f - ox) * ixr, t2x = (1.f - ox) * ixr;
  float t1y = (-1.f - oy) * iyr, t2y = (1.f - oy) * iyr;
  float t1z = (-1.f - oz) * izr, t2z = (1.f - oz) * izr;
  float nearv = fmaxf(fmaxf(fminf(t1x, t2x), fminf(t1y, t2y)), fminf(t1z, t2z));
  nearv = fmaxf(nearv, 0.2f);
  float farv = fminf(fminf(fmaxf(t1x, t2x), fmaxf(t1y, t2y)), fmaxf(t1z, t2z));
  farv = fmaxf(farv, nearv + 0.0001f);
  const float span = farv - nearv;

  // ---------------- weight fragments (all up front) ----------------
  bf16x8 a2[2], c1a[4], k1a[4], argb[2];
  if (PREP) {
#pragma unroll
    for (int kt = 0; kt < 2; kt++) {
      a2[kt]   = __builtin_bit_cast(bf16x8, wsp[lane * 2 + kt]);
      argb[kt] = __builtin_bit_cast(bf16x8, wsp[640 + lane * 2 + kt]);
    }
#pragma unroll
    for (int ht = 0; ht < 4; ht++) {
      c1a[ht] = __builtin_bit_cast(bf16x8, wsp[128 + lane * 4 + ht]);
      k1a[ht] = __builtin_bit_cast(bf16x8, wsp[384 + lane * 4 + ht]);
    }
  } else {
#pragma unroll
    for (int kt = 0; kt < 2; kt++)
#pragma unroll
      for (int j = 0; j < 8; j++) {
        a2[kt][j] = f2bf(Wd2[(32 * kt + 8 * o + j) * 16 + c16]);
        int h = 32 * kt + 8 * o + j;
        float w = 0.f;
        if (c16 == 0)      w = Wc2[h * 3 + 0];
        else if (c16 == 4) w = Wc2[h * 3 + 1];
        else if (c16 == 8) w = Wc2[h * 3 + 2];
        argb[kt][j] = f2bf(w);
      }
#pragma unroll
    for (int ht = 0; ht < 4; ht++) {
      const int hc_ = pi_row(ht, c16);
      const int hk_ = 16 * ht + c16;
#pragma unroll
      for (int j = 0; j < 8; j++) {
        int k = 8 * o + j;
        float wc = 0.f, wk = 0.f;
        if (k >= 1 && k <= 15) wc = Wc1[(k + 2) * 64 + hc_];
        else if (k >= 16 && k <= 18) wc = Wc1[(k - 16) * 64 + hc_];
        else if (k == 19) wc = bc1[hc_];
        if (k == 0) wk = Wk1[15 * 64 + hk_];
        else if (k <= 15) wk = Wk1[(k - 1) * 64 + hk_];
        else if (k == 19) wk = bk1[hk_];
        c1a[ht][j] = f2bf(wc);
        k1a[ht][j] = f2bf(wk);
      }
    }
  }

  // A1 linearized + per-lane constants
  float p1[16], q1[16];
#pragma unroll
  for (int kt = 0; kt < 2; kt++)
#pragma unroll
    for (int j = 0; j < 8; j++) {
      int h = 32 * kt + 8 * o + j;
      float w0 = Wd1[h], w1 = Wd1[64 + h], w2 = Wd1[128 + h];
      p1[8 * kt + j] = fmaf(w0, ox, fmaf(w1, oy, fmaf(w2, oz, bd1[h])));
      q1[8 * kt + j] = fmaf(w0, dx, fmaf(w1, dy, w2 * dz));
    }
  f32x4 bd2v = {bd2[4 * o], bd2[4 * o + 1], bd2[4 * o + 2], bd2[4 * o + 3]};
  f32x4 bc2i = {0.f, 0.f, 0.f, 0.f};
  if (o < 3) bc2i[0] = bc2[o];         // bias for channel o at D-row 4o
  const f32x4 zacc = {0.f, 0.f, 0.f, 0.f};

  // ================ PHASE 1: density MLP ====================================
  // unified geo write pointer (o<2 -> geoA cols 4o, o>=2 -> geoB cols 4(o-2))
  short* gws = ((o < 2) ? &geoA[0][4 * o] : &geoB[0][4 * (o - 2)]) + c16 * 8;
  float* tpw = &tmp[c16];
  float zt = nearv + span * ((float)c16 * (1.f / 255.f));
  const float ztstep = span * (16.f / 255.f);
#pragma unroll 2
  for (int mt = 0; mt < 16; mt++) {
    bf16x8 h1f[2];
#pragma unroll
    for (int kt = 0; kt < 2; kt++) {
      i32x4 tv;
#pragma unroll
      for (int q = 0; q < 4; q++) {
        float a = fmaxf(fmaf(q1[8 * kt + 2 * q],     zt, p1[8 * kt + 2 * q]),     0.f);
        float b = fmaxf(fmaf(q1[8 * kt + 2 * q + 1], zt, p1[8 * kt + 2 * q + 1]), 0.f);
        tv[q] = cvtpk(a, b);          // inputs are fmaxf outputs: hazard-safe
      }
      h1f[kt] = __builtin_bit_cast(bf16x8, tv);
    }
    f32x4 acc = bd2v;
    acc = MFMA(a2[0], h1f[0], acc);
    acc = MFMA(a2[1], h1f[1], acc);
    float sgm = __expf(acc[0]);                    // valid on o==0
    i32x2 pkv;
    pkv[0] = pkperm((o == 0) ? sgm : acc[0], acc[1]);  // 3-op pack, hazard-safe
    pkv[1] = pkperm(acc[2], acc[3]);
    *(i32x2*)gws = pkv;
    if (o == 0) *tpw = sgm;
    gws += 128; tpw += 16; zt += ztstep;
  }

  // ================ transmittance scan (t-layout fp32) =======================
  float z[4], wm[4];
  float ws, swz, depth, var, cx, cy, cz;
  __syncthreads();                                 // single-wave: near-free
  {
    f32x4 sgv = *(f32x4*)&tmp[lane * 4];
    float alpha[4], v[4], m[4];
#pragma unroll
    for (int i = 0; i < 4; i++) {
      int t = lane * 4 + i;
      z[i] = nearv + span * ((float)t * (1.f / 255.f));
      float delta = (t < 255) ? span * (1.f / 255.f) : span * (1.f / 256.f);
      alpha[i] = 1.f - __expf(-delta * sgv[i]);
      v[i] = 1.f - alpha[i] + 1e-15f;
    }
    m[0] = 1.f; m[1] = v[0]; m[2] = m[1] * v[1]; m[3] = m[2] * v[2];
    float ip = m[3] * v[3];
#pragma unroll
    for (int off = 1; off < 64; off <<= 1) {
      float u = __shfl_up(ip, off, 64);
      if (lane >= off) ip *= u;
    }
    float E = __shfl_up(ip, 1, 64);
    if (lane == 0) E = 1.f;
    ws = 0.f; swz = 0.f; cx = 0.f; cy = 0.f; cz = 0.f;
#pragma unroll
    for (int i = 0; i < 4; i++) {
      float w = alpha[i] * (E * m[i]);
      wm[i] = (w > 0.0001f) ? w : 0.f;
      ws += wm[i];
      swz = fmaf(wm[i], z[i], swz);
      float xc = fminf(fmaxf(fmaf(dx, z[i], ox), -1.f), 1.f);
      float yc = fminf(fmaxf(fmaf(dy, z[i], oy), -1.f), 1.f);
      float zc = fminf(fmaxf(fmaf(dz, z[i], oz), -1.f), 1.f);
      cx = fmaf(wm[i], xc, cx); cy = fmaf(wm[i], yc, cy); cz = fmaf(wm[i], zc, cz);
    }
    // wm -> TRANSPOSED buffer: tmpT[s&15][s>>4]; sample s = lane*4+i
#pragma unroll
    for (int i = 0; i < 4; i++) {
      int s = lane * 4 + i;
      tmpT[s & 15][s >> 4] = wm[i];
    }
    ws = waveAllSum(ws); swz = waveAllSum(swz);
    cx = waveAllSum(cx); cy = waveAllSum(cy); cz = waveAllSum(cz);
    depth = swz / dn;
    var = 0.f;
#pragma unroll
    for (int i = 0; i < 4; i++) {
      float dd = depth - z[i] / dn;
      var = fmaf(wm[i], dd * dd, var);
    }
    var = waveAllSum(var);
  }
  if (lane == 0) {
    out[OFF_DEPTH + ray] = depth;
    out[OFF_VAR + ray]   = var;
    out[OFF_COORD + ray * 3 + 0] = cx;
    out[OFF_COORD + ray * 3 + 1] = cy;
    out[OFF_COORD + ray * 3 + 2] = cz;
    // per-wave constant B-fragment slots for o>=2 lanes
    i32x4 dv; dv[0] = pk2(dx, dy); dv[1] = pk2(dz, 1.f); dv[2] = 0; dv[3] = 0;
    slots4[0] = dv;                                // dirs(k16-18) + bias-one(k19)
    i32x4 zv = {0, 0, 0, 0};
    slots4[1] = zv;                                // zeros (o==3 rows)
  }
  __syncthreads();   // order slot/wm writes before phase-2 reads (1 wave: cheap)

  // ================ PHASE 2: color + clip MLPs, fully MFMA ===================
  float ia = 0.f;                                  // image partial (channel o)
  float gp[4][4];
#pragma unroll
  for (int ht = 0; ht < 4; ht++)
#pragma unroll
    for (int r = 0; r < 4; r++) gp[ht][r] = 0.f;

  // single unified B-fragment stream (B1a color AND B2a clip share it)
  const short* pBs = ((o == 0) ? &geoA[0][0]
                    : (o == 1) ? &geoB[0][0]
                    : (o == 2) ? (const short*)&slots4[0]
                               : (const short*)&slots4[1]);
  const int sstep = (o < 2) ? 8 : 0;               // shorts per sample row
  pBs += c16 * sstep;
  const int stepB = 16 * sstep;                    // shorts per mt tile
  // rgbs pointer: lane (c16,o) owns sample s=mt*16+c16, channel o (o<3)
  float* rgbp = out + OFF_RGBS + (long)ray * 768 + c16 * 3 + o;

#pragma unroll 1
  for (int tq = 0; tq < 4; tq++) {
    const f32x4 wmq = *(const f32x4*)&tmpT[c16][4 * tq];   // 4 tiles' wm at once
#pragma unroll
    for (int j = 0; j < 4; j++) {                  // fully unrolled: ILP + static idx
      const bf16x8 bfr = *(const bf16x8*)pBs;      // unified B-fragment
      const float wmv = wmq[j];
      // ---- B1a: HC = Wc1''(pi-rows) @ CIN''; outputs lane-local in k-order ----
      i32x4 h0v, h1v;
#pragma unroll
      for (int ht = 0; ht < 4; ht++) {
        f32x4 hc = MFMA(c1a[ht], bfr, zacc);
        int u0 = cvtpk(fmaxf(hc[0], 0.f), fmaxf(hc[1], 0.f));  // fmaxf-filtered
        int u1 = cvtpk(fmaxf(hc[2], 0.f), fmaxf(hc[3], 0.f));
        if (ht == 0)      { h0v[0] = u0; h0v[1] = u1; }
        else if (ht == 1) { h0v[2] = u0; h0v[3] = u1; }
        else if (ht == 2) { h1v[0] = u0; h1v[1] = u1; }
        else              { h1v[2] = u0; h1v[3] = u1; }
      }
      // ---- B1b: rgb = Wc2^T @ relu(HC); channel o at D-row 4o -> racc[0] ----
      f32x4 racc = bc2i;
      racc = MFMA(argb[0], __builtin_bit_cast(bf16x8, h0v), racc);
      racc = MFMA(argb[1], __builtin_bit_cast(bf16x8, h1v), racc);
      // spread-channel epilogue: every lane handles ONE (sample,channel)
      {
        float sv = __builtin_amdgcn_rcpf(1.f + __expf(-racc[0]));
        sv = (wmv > 0.f) ? sv : 0.f;
        if (o < 3) *rgbp = sv;
        ia = fmaf(wmv, sv, ia);                    // channel-o partial
      }
      // ---- B2a: HK = Wk1''(unified-k) @ same bfr ----
#pragma unroll
      for (int ht = 0; ht < 4; ht++) {
        f32x4 hk = MFMA(k1a[ht], bfr, zacc);
#pragma unroll
        for (int r = 0; r < 4; r++)
          gp[ht][r] = fmaf(wmv, fmaxf(hk[r], 0.f), gp[ht][r]);
      }
      pBs += stepB; rgbp += 48;
    }
  }

  // image: reduce channel-o partial over c16 (within each 16-lane group)
  ia += __shfl_xor(ia, 1, 64); ia += __shfl_xor(ia, 2, 64);
  ia += __shfl_xor(ia, 4, 64); ia += __shfl_xor(ia, 8, 64);
  if (c16 == 0 && o < 3) out[OFF_IMG + ray * 3 + o] = ia + (1.f - ws);

  // ---- B2b: reduce g over samples, then clip = g @ Wk2 + ws*bk2 ----
#pragma unroll
  for (int ht = 0; ht < 4; ht++)
#pragma unroll
    for (int r = 0; r < 4; r++) {
      float g = gp[ht][r];
      g += __shfl_xor(g, 1, 64); g += __shfl_xor(g, 2, 64);
      g += __shfl_xor(g, 4, 64); g += __shfl_xor(g, 8, 64);
      gp[ht][r] = g;                 // g[h], h = 16*ht + 4*o + r
    }
  {
    const int k2 = 2 * c16;
    const float2* w2 = (const float2*)Wk2;   // [h][16] float2 pairs
    float cp0 = 0.f, cp1 = 0.f;
#pragma unroll
    for (int ht = 0; ht < 4; ht++)
#pragma unroll
      for (int r = 0; r < 4; r++) {
        int h = 16 * ht + 4 * o + r;
        float2 wv = w2[h * 16 + c16];
        cp0 = fmaf(gp[ht][r], wv.x, cp0);
        cp1 = fmaf(gp[ht][r], wv.y, cp1);
      }
    cp0 += __shfl_xor(cp0, 16, 64); cp0 += __shfl_xor(cp0, 32, 64);
    cp1 += __shfl_xor(cp1, 16, 64); cp1 += __shfl_xor(cp1, 32, 64);
    cp0 = fmaf(ws, bk2[k2], cp0);
    cp1 = fmaf(ws, bk2[k2 + 1], cp1);
    if (lane < 16) {
      out[OFF_CLIP + ray * 32 + k2]     = cp0;
      out[OFF_CLIP + ray * 32 + k2 + 1] = cp1;
    }
  }
}

extern "C" void kernel_launch(void* const* d_in, const int* in_sizes, int n_in,
                              void* d_out, int out_size, void* d_ws, size_t ws_size,
                              hipStream_t stream) {
  const bool prep = (ws_size >= 12288);
  if (prep) {
    prep_kernel<<<1, 64, 0, stream>>>((fpp)d_in[5], (fpp)d_in[7], (fpp)d_in[11],
                                      (fpp)d_in[9], (fpp)d_in[8], (fpp)d_in[12],
                                      (uint4*)d_ws);
    nerf_kernel<true><<<NRAYS, 64, 0, stream>>>(
        (fpp)d_in[0], (fpp)d_in[1], (fpp)d_in[2],
        (fpp)d_in[3], (fpp)d_in[4], (fpp)d_in[5], (fpp)d_in[6],
        (fpp)d_in[7], (fpp)d_in[8], (fpp)d_in[9], (fpp)d_in[10],
        (fpp)d_in[11], (fpp)d_in[12], (fpp)d_in[13], (fpp)d_in[14],
        (const uint4*)d_ws, (float*)d_out);
  } else {
    nerf_kernel<false><<<NRAYS, 64, 0, stream>>>(
        (fpp)d_in[0], (fpp)d_in[1], (fpp)d_in[2],
        (fpp)d_in[3], (fpp)d_in[4], (fpp)d_in[5], (fpp)d_in[6],
        (fpp)d_in[7], (fpp)d_in[8], (fpp)d_in[9], (fpp)d_in[10],
        (fpp)d_in[11], (fpp)d_in[12], (fpp)d_in[13], (fpp)d_in[14],
        (const uint4*)d_ws, (float*)d_out);
  }
}